// Round 2
// baseline (120.927 us; speedup 1.0000x reference)
//
#include <hip/hip_runtime.h>
#include <hip/hip_bf16.h>

// IsolaCLIPLoss: out = 3*align + 0.5*(log-mean-exp uniformity of img Gram + txt Gram)
// N=8192, D=512 fp32 inputs.
//
// R14: break the 2-barrier plateau (T3/T4 minimum form).
// Evidence from R13 profile: timed region = ~46us workspace poison (fill of
// 8192^2*4 B at HBM rate, harness-side, untouchable) + gram ~44 + normalize
// ~8 + finalize/gaps ~6. fp8->fp4 port moved gram only 49.7->~44 despite 2x
// MFMA rate and 1/2 bytes => gram is NOT compute/BW-bound; it is the
// stage->vmcnt(0)->barrier->compute serialization (2 stages, 2 blk/CU).
// Fix: double-buffer LDS (96 KB), issue BOTH K-stages' global_load_lds
// up-front, counted s_waitcnt vmcnt(6) so stage-1 loads fly during stage-0
// compute; raw s_barrier (no compiler vmcnt(0) drain); sched_barrier(0)
// pins issue order and fences reordering (guide rules #18/#21).
// Geometry: 512 thr / 8 waves, per-wave 64x64 (acc 2x2x16), 1 blk/CU
// (LDS-bound) = same 2 waves/SIMD as R12 but with explicit overlap.
// The PROVEN conflict-free 128B-row stride+swizzle is byte-identical.
// Predict: gram ~44 -> ~18-25us, total 111 -> ~82-92us, conflicts stay 0.

#define NROWS 8192
#define DBYTES 256         // row stride in BYTES (fp4: 512 elems * 0.5)
#define NBLK  1056         // sum_{I=0}^{31} (64-2I): 256-row x 128-col tiles
#define SCALE4 0x7B7B7B7B  // E8M0 byte 123 = 2^-4, splatted

typedef __attribute__((ext_vector_type(8)))  int   int8v;
typedef __attribute__((ext_vector_type(4)))  int   int4v;
typedef __attribute__((ext_vector_type(16))) float float16v;

__device__ inline void load_lds16(const void* g, void* l) {
    __builtin_amdgcn_global_load_lds(
        (const __attribute__((address_space(1))) void*)g,
        (__attribute__((address_space(3))) void*)l, 16, 0, 0);
}

__device__ inline int swz(int r) { return (r ^ (r >> 3)) & 7; }

// e2m1 code for x (already scaled): grid {0,.5,1,1.5,2,3,4,6}, RTNE midpoints.
__device__ inline unsigned fp4_code(float x) {
    const float a = fabsf(x);
    unsigned c = (a < 0.25f) ? 0u : (a < 0.75f) ? 1u : (a < 1.25f) ? 2u :
                 (a < 1.75f) ? 3u : (a < 2.5f)  ? 4u : (a < 3.5f)  ? 5u :
                 (a < 5.0f)  ? 6u : 7u;
    return c | ((__float_as_uint(x) >> 28) & 8u);
}

// ---------------------------------------------------------------- normalize
// One wave per 4-row group; lane L covers elems [8L, 8L+8) of its row ->
// packs 8 fp4 codes into one int, stored at row*64 + L (coalesced).
// UNCHANGED from R12 (isolate the gram restructure for attribution).
__global__ __launch_bounds__(256) void normalize_kernel(
    const float* __restrict__ img, const float* __restrict__ txt,
    int* __restrict__ nimg, int* __restrict__ ntxt,   // fp4-packed [8192][64]
    float* __restrict__ alignp,   // [2048] per-block partial of sum_i ndot_i
    float* __restrict__ S)        // [64] gram accumulators -> zeroed here
{
    if (blockIdx.x == 0 && threadIdx.x < 64) S[threadIdx.x] = 0.0f;

    const int lane = threadIdx.x & 63;
    const int wave = threadIdx.x >> 6;
    const int row  = blockIdx.x * 4 + wave;

    const float4* pi = (const float4*)(img + (size_t)row * 512);
    const float4* pt = (const float4*)(txt + (size_t)row * 512);
    const float4 i0 = pi[2 * lane], i1 = pi[2 * lane + 1];   // elems 8L..8L+7
    const float4 t0 = pt[2 * lane], t1 = pt[2 * lane + 1];

    float ssi = i0.x*i0.x + i0.y*i0.y + i0.z*i0.z + i0.w*i0.w
              + i1.x*i1.x + i1.y*i1.y + i1.z*i1.z + i1.w*i1.w;
    float sst = t0.x*t0.x + t0.y*t0.y + t0.z*t0.z + t0.w*t0.w
              + t1.x*t1.x + t1.y*t1.y + t1.z*t1.z + t1.w*t1.w;
    float dot = i0.x*t0.x + i0.y*t0.y + i0.z*t0.z + i0.w*t0.w
              + i1.x*t1.x + i1.y*t1.y + i1.z*t1.z + i1.w*t1.w;

    #pragma unroll
    for (int off = 1; off < 64; off <<= 1) {
        ssi += __shfl_xor(ssi, off);
        sst += __shfl_xor(sst, off);
        dot += __shfl_xor(dot, off);
    }
    const float inv_i = 1.0f / fmaxf(sqrtf(ssi), 1e-12f);
    const float inv_t = 1.0f / fmaxf(sqrtf(sst), 1e-12f);
    const float si = 16.0f * inv_i;   // quantize at 2^4 scale
    const float st = 16.0f * inv_t;

    unsigned wi = 0, wt = 0;
    wi |= fp4_code(i0.x * si)       | (fp4_code(i0.y * si) << 4)
       |  (fp4_code(i0.z * si) << 8)| (fp4_code(i0.w * si) << 12)
       |  (fp4_code(i1.x * si) <<16)| (fp4_code(i1.y * si) << 20)
       |  (fp4_code(i1.z * si) <<24)| (fp4_code(i1.w * si) << 28);
    wt |= fp4_code(t0.x * st)       | (fp4_code(t0.y * st) << 4)
       |  (fp4_code(t0.z * st) << 8)| (fp4_code(t0.w * st) << 12)
       |  (fp4_code(t1.x * st) <<16)| (fp4_code(t1.y * st) << 20)
       |  (fp4_code(t1.z * st) <<24)| (fp4_code(t1.w * st) << 28);

    nimg[row * 64 + lane] = (int)wi;
    ntxt[row * 64 + lane] = (int)wt;

    __shared__ float r4[4];
    if (lane == 0) r4[wave] = dot * inv_i * inv_t;
    __syncthreads();
    if (threadIdx.x == 0)
        alignp[blockIdx.x] = r4[0] + r4[1] + r4[2] + r4[3];
}

// ---------------------------------------------------------------- gram + lme
// Block (I, j): rows [256I, 256I+256) x cols [128j, 128j+128), j >= 2I.
// 8 waves (512 thr): wm = w&3 row-quarter (64), wn = w>>2 col-half (64);
// per-wave 64x64 via 2x2 of 32x32x64 fp4 MFMA. BK = 256 elems = 128 B;
// 2 k0 stages DOUBLE-BUFFERED: all 12 global_load_lds per wave issued
// up-front, vmcnt(6) gates stage 0, vmcnt(0)+barrier gates stage 1.
__global__ __launch_bounds__(512, 2) void gram_kernel(
    const unsigned char* __restrict__ A0,   // fp4 [8192][256B], blockIdx.y==0
    const unsigned char* __restrict__ A1,   // blockIdx.y==1
    float* __restrict__ S)                  // [64] spread accumulators
{
    // Decode b -> (I, j): cum(I) = I*(65-I), j = 2I + (b - cum(I))
    const int b = blockIdx.x;
    int I = (int)((65.0f - sqrtf(4225.0f - 4.0f * (float)b)) * 0.5f);
    while ((I + 1) * (64 - I) <= b) ++I;
    while (I * (65 - I) > b) --I;
    const int j = 2 * I + (b - I * (65 - I));

    const unsigned char* __restrict__ A = blockIdx.y ? A1 : A0;
    const int tid  = threadIdx.x;
    const int lane = tid & 63;
    const int wave = tid >> 6;
    const int wm = wave & 3;                   // row quarter (64 rows)
    const int wn = wave >> 2;                  // col half (64 cols)
    const int lr = lane & 31;                  // row-in-subtile
    const int h  = lane >> 5;                  // K-half select

    const unsigned char* gA = A + (size_t)I * 256 * DBYTES;
    const unsigned char* gB = A + (size_t)j * 128 * DBYTES;

    __shared__ __align__(16) unsigned char ldsA[2][256 * 128];   // 64 KB
    __shared__ __align__(16) unsigned char ldsB[2][128 * 128];   // 32 KB

    float16v acc[2][2];
    #pragma unroll
    for (int a = 0; a < 2; ++a)
        #pragma unroll
        for (int c = 0; c < 2; ++c)
            #pragma unroll
            for (int r = 0; r < 16; ++r) acc[a][c][r] = 0.0f;

    // ---- issue BOTH stages' loads up-front (6 VMEM insts/wave per stage).
    // LDS slot lane-contiguous (wave-uniform base + lane*16, required by
    // global_load_lds); global chunk cl = cp ^ swz(r) (PROVEN geometry).
    #pragma unroll
    for (int s = 0; s < 2; ++s) {
        const int k0 = s * 128;
        #pragma unroll
        for (int rnd = 0; rnd < 4; ++rnd) {          // A: 256 rows x 128 B
            const int slot = rnd * 8192 + tid * 16;
            const int r    = slot >> 7;
            const int cp   = (slot >> 4) & 7;
            const int cl   = cp ^ swz(r);
            load_lds16(gA + (size_t)r * DBYTES + k0 + cl * 16, &ldsA[s][slot]);
        }
        #pragma unroll
        for (int rnd = 0; rnd < 2; ++rnd) {          // B: 128 rows x 128 B
            const int slot = rnd * 8192 + tid * 16;
            const int r    = slot >> 7;
            const int cp   = (slot >> 4) & 7;
            const int cl   = cp ^ swz(r);
            load_lds16(gB + (size_t)r * DBYTES + k0 + cl * 16, &ldsB[s][slot]);
        }
        __builtin_amdgcn_sched_barrier(0);   // pin issue order: s0 before s1
    }

    // stage 0 landed (6 newest = stage 1 still in flight under compute 0)
    asm volatile("s_waitcnt vmcnt(6)" ::: "memory");
    __builtin_amdgcn_sched_barrier(0);
    __builtin_amdgcn_s_barrier();
    __builtin_amdgcn_sched_barrier(0);

    #pragma unroll
    for (int s = 0; s < 2; ++s) {
        #pragma unroll
        for (int kk = 0; kk < 4; ++kk) {       // four K=64 steps per stage
            const int c0 = kk * 2 + h;         // one 16B chunk per lane
            int8v av[2], bv[2];
            #pragma unroll
            for (int mt = 0; mt < 2; ++mt) {
                const int r = wm * 64 + mt * 32 + lr;
                *((int4v*)&av[mt]) =
                    *(const int4v*)&ldsA[s][r * 128 + (c0 ^ swz(r)) * 16];
                *((int4v*)&av[mt] + 1) = (int4v){0, 0, 0, 0};
            }
            #pragma unroll
            for (int nt = 0; nt < 2; ++nt) {
                const int r = wn * 64 + nt * 32 + lr;
                *((int4v*)&bv[nt]) =
                    *(const int4v*)&ldsB[s][r * 128 + (c0 ^ swz(r)) * 16];
                *((int4v*)&bv[nt] + 1) = (int4v){0, 0, 0, 0};
            }
            #pragma unroll
            for (int mt = 0; mt < 2; ++mt)
                #pragma unroll
                for (int nt = 0; nt < 2; ++nt)
                    acc[mt][nt] = __builtin_amdgcn_mfma_scale_f32_32x32x64_f8f6f4(
                        av[mt], bv[nt], acc[mt][nt],
                        4, 4,                   // cbsz=blgp=4: fp4 e2m1
                        0, SCALE4,              // opsel_a, scale_a (2^-4)
                        0, SCALE4);             // opsel_b, scale_b (2^-4)
        }
        if (s == 0) {
            // stage 1 fully landed (should be free: hidden under compute 0)
            asm volatile("s_waitcnt vmcnt(0)" ::: "memory");
            __builtin_amdgcn_s_barrier();
            __builtin_amdgcn_sched_barrier(0);
        }
    }

    // Epilogue: per-wave uniform symmetry weight, exp-sum, block reduce.
    const int r128 = 2 * I + (wm >> 1);        // global 128-row index
    const float wv = (j > r128) ? 2.0f : ((j == r128) ? 1.0f : 0.0f);
    float s = 0.0f;
    #pragma unroll
    for (int mt = 0; mt < 2; ++mt)
        #pragma unroll
        for (int nt = 0; nt < 2; ++nt)
            #pragma unroll
            for (int r2 = 0; r2 < 16; ++r2) {
                const float g = acc[mt][nt][r2];
                s += __expf(4.0f * fminf(g, 1.0f) - 4.0f);
            }
    s *= wv;
    #pragma unroll
    for (int off = 32; off; off >>= 1) s += __shfl_down(s, off);
    __shared__ float ps[8];
    if (lane == 0) ps[wave] = s;
    __syncthreads();
    if (tid == 0) {
        const float tot = ps[0] + ps[1] + ps[2] + ps[3]
                        + ps[4] + ps[5] + ps[6] + ps[7];
        atomicAdd(&S[blockIdx.y * 32 + (blockIdx.x & 31)], tot);
    }
}

// ---------------------------------------------------------------- finalize
__global__ __launch_bounds__(256) void finalize_kernel(
    const float* __restrict__ S,       // [64]
    const float* __restrict__ alignp,  // [2048]
    float* __restrict__ out)
{
    const int tid = threadIdx.x;
    float a = 0.0f;
    #pragma unroll
    for (int k = 0; k < 8; ++k) a += alignp[tid + 256 * k];
    #pragma unroll
    for (int off = 32; off; off >>= 1) a += __shfl_down(a, off);
    __shared__ float r4[4];
    if ((tid & 63) == 0) r4[tid >> 6] = a;
    __syncthreads();
    if (tid == 0) {
        const double A = (double)r4[0] + r4[1] + r4[2] + r4[3];
        double si = 0.0, st = 0.0;
        for (int k = 0; k < 32; ++k) { si += S[k]; st += S[32 + k]; }
        const double align = 2.0 - 2.0 * A / (double)NROWS;
        const double n2 = (double)NROWS * (double)NROWS;
        const double unif = 0.5 * (log(si / n2) + log(st / n2));
        out[0] = (float)(3.0 * align + unif);
    }
}

// ---------------------------------------------------------------- launch
extern "C" void kernel_launch(void* const* d_in, const int* in_sizes, int n_in,
                              void* d_out, int out_size, void* d_ws, size_t ws_size,
                              hipStream_t stream) {
    const float* img = (const float*)d_in[0];
    const float* txt = (const float*)d_in[1];
    char* ws = (char*)d_ws;
    int* nimg = (int*)ws;                                        // 2 MB fp4
    int* ntxt = (int*)(ws + (size_t)NROWS * DBYTES);             // 2 MB fp4
    float* S      = (float*)(ws + 2 * (size_t)NROWS * DBYTES);   // [64]
    float* alignp = S + 64;                                      // [2048]

    normalize_kernel<<<NROWS / 4, 256, 0, stream>>>(img, txt, nimg, ntxt, alignp, S);
    dim3 grid(NBLK, 2);
    gram_kernel<<<grid, 512, 0, stream>>>((const unsigned char*)nimg,
                                          (const unsigned char*)ntxt, S);
    finalize_kernel<<<1, 256, 0, stream>>>(S, alignp, (float*)d_out);
}

// Round 3
// 115.146 us; speedup vs baseline: 1.0502x; 1.0502x over previous
//
#include <hip/hip_runtime.h>
#include <hip/hip_bf16.h>

// IsolaCLIPLoss: out = 3*align + 0.5*(log-mean-exp uniformity of img Gram + txt Gram)
// N=8192, D=512 fp32 inputs.
//
// R15: persistent gram (T3+T4, rolling pipeline).
// R14 post-mortem: gram 45.7us with MfmaUtil 14%, VALUBusy 38%, occ 16.5%,
// FETCH 16MB @4.5% HBM -> neither pipe saturated = latency-bound. 512-thr /
// 96.5KB-LDS blocks forced 1 blk/CU: lost R12's inter-block overlap, and the
// serial per-block chain (issue->wait->compute->epilogue ~5.5us) ran naked
// for 8.25 dispatch rounds. Ceiling arithmetic: MFMA 532k insts = 7.7us,
// L2 staging 266MB = 7.7us, LDS reads ~7us -> a filled pipeline lands
// 10-15us.
// Fix: persistent kernel. 512 blocks (2/CU, 64KB LDS), each loops over ~8
// jobs = 128x128 upper-triangle tiles (2080/matrix x 2). Per job 2 K-stages
// (BK=256 elems = 128B rows, the PROVEN conflict-free stride+swizzle,
// byte-identical). Rolling dbuf: stage(u+1) -> vmcnt(8) counted (never 0
// mid-loop) -> barrier -> compute(u) -> barrier. Next unit's loads stay in
// flight across barriers+compute for the kernel's whole life; prologue
// latency + epilogue paid once per block, dispatch rounds eliminated.
// Predict: gram -> 13-20us, MfmaUtil 35-50%, conflicts ~0, total ~88-96us.

#define NROWS 8192
#define DBYTES 256         // row stride in BYTES (fp4: 512 elems * 0.5)
#define NTRI  2080         // 64*65/2 upper-tri 128x128 tiles per matrix
#define NJOBS 4160         // x2 matrices
#define GRAMBLK 512        // persistent blocks (2 per CU)
#define SCALE4 0x7B7B7B7B  // E8M0 byte 123 = 2^-4, splatted

typedef __attribute__((ext_vector_type(8)))  int   int8v;
typedef __attribute__((ext_vector_type(4)))  int   int4v;
typedef __attribute__((ext_vector_type(16))) float float16v;

__device__ inline void load_lds16(const void* g, void* l) {
    __builtin_amdgcn_global_load_lds(
        (const __attribute__((address_space(1))) void*)g,
        (__attribute__((address_space(3))) void*)l, 16, 0, 0);
}

__device__ inline int swz(int r) { return (r ^ (r >> 3)) & 7; }

// e2m1 code for x (already scaled): grid {0,.5,1,1.5,2,3,4,6}, RTNE midpoints.
__device__ inline unsigned fp4_code(float x) {
    const float a = fabsf(x);
    unsigned c = (a < 0.25f) ? 0u : (a < 0.75f) ? 1u : (a < 1.25f) ? 2u :
                 (a < 1.75f) ? 3u : (a < 2.5f)  ? 4u : (a < 3.5f)  ? 5u :
                 (a < 5.0f)  ? 6u : 7u;
    return c | ((__float_as_uint(x) >> 28) & 8u);
}

// ---------------------------------------------------------------- normalize
// UNCHANGED from R12 (isolate gram restructure for attribution).
__global__ __launch_bounds__(256) void normalize_kernel(
    const float* __restrict__ img, const float* __restrict__ txt,
    int* __restrict__ nimg, int* __restrict__ ntxt,   // fp4-packed [8192][64]
    float* __restrict__ alignp,   // [2048] per-block partial of sum_i ndot_i
    float* __restrict__ S)        // [64] gram accumulators -> zeroed here
{
    if (blockIdx.x == 0 && threadIdx.x < 64) S[threadIdx.x] = 0.0f;

    const int lane = threadIdx.x & 63;
    const int wave = threadIdx.x >> 6;
    const int row  = blockIdx.x * 4 + wave;

    const float4* pi = (const float4*)(img + (size_t)row * 512);
    const float4* pt = (const float4*)(txt + (size_t)row * 512);
    const float4 i0 = pi[2 * lane], i1 = pi[2 * lane + 1];   // elems 8L..8L+7
    const float4 t0 = pt[2 * lane], t1 = pt[2 * lane + 1];

    float ssi = i0.x*i0.x + i0.y*i0.y + i0.z*i0.z + i0.w*i0.w
              + i1.x*i1.x + i1.y*i1.y + i1.z*i1.z + i1.w*i1.w;
    float sst = t0.x*t0.x + t0.y*t0.y + t0.z*t0.z + t0.w*t0.w
              + t1.x*t1.x + t1.y*t1.y + t1.z*t1.z + t1.w*t1.w;
    float dot = i0.x*t0.x + i0.y*t0.y + i0.z*t0.z + i0.w*t0.w
              + i1.x*t1.x + i1.y*t1.y + i1.z*t1.z + i1.w*t1.w;

    #pragma unroll
    for (int off = 1; off < 64; off <<= 1) {
        ssi += __shfl_xor(ssi, off);
        sst += __shfl_xor(sst, off);
        dot += __shfl_xor(dot, off);
    }
    const float inv_i = 1.0f / fmaxf(sqrtf(ssi), 1e-12f);
    const float inv_t = 1.0f / fmaxf(sqrtf(sst), 1e-12f);
    const float si = 16.0f * inv_i;   // quantize at 2^4 scale
    const float st = 16.0f * inv_t;

    unsigned wi = 0, wt = 0;
    wi |= fp4_code(i0.x * si)       | (fp4_code(i0.y * si) << 4)
       |  (fp4_code(i0.z * si) << 8)| (fp4_code(i0.w * si) << 12)
       |  (fp4_code(i1.x * si) <<16)| (fp4_code(i1.y * si) << 20)
       |  (fp4_code(i1.z * si) <<24)| (fp4_code(i1.w * si) << 28);
    wt |= fp4_code(t0.x * st)       | (fp4_code(t0.y * st) << 4)
       |  (fp4_code(t0.z * st) << 8)| (fp4_code(t0.w * st) << 12)
       |  (fp4_code(t1.x * st) <<16)| (fp4_code(t1.y * st) << 20)
       |  (fp4_code(t1.z * st) <<24)| (fp4_code(t1.w * st) << 28);

    nimg[row * 64 + lane] = (int)wi;
    ntxt[row * 64 + lane] = (int)wt;

    __shared__ float r4[4];
    if (lane == 0) r4[wave] = dot * inv_i * inv_t;
    __syncthreads();
    if (threadIdx.x == 0)
        alignp[blockIdx.x] = r4[0] + r4[1] + r4[2] + r4[3];
}

// ---------------------------------------------------------------- gram + lme
// Job t in [0,4160): matrix m = t>=2080, tile tt = t - m*2080 -> (i,j) with
// i<=j<64 over 128x128 tiles. Weight 2 off-diag, 1 diag (mirror symmetry).
__device__ inline void decode_job(int t,
        const unsigned char* __restrict__ A0,
        const unsigned char* __restrict__ A1,
        const unsigned char*& pA, const unsigned char*& pB,
        float& w0, float& w1)
{
    const int m  = (t >= NTRI) ? 1 : 0;
    const int tt = t - m * NTRI;
    // cum(i) = 64i - i(i-1)/2 ; solve i^2 - 129i + 2tt = 0
    int i = (int)((129.0f - sqrtf(16641.0f - 8.0f * (float)tt)) * 0.5f);
    while (64 * (i + 1) - ((i + 1) * i) / 2 <= tt) ++i;
    while (64 * i - (i * (i - 1)) / 2 > tt) --i;
    const int j = i + (tt - (64 * i - (i * (i - 1)) / 2));
    const unsigned char* M = m ? A1 : A0;
    pA = M + (size_t)i * 128 * DBYTES;
    pB = M + (size_t)j * 128 * DBYTES;
    const float w = (j > i) ? 2.0f : 1.0f;
    w0 = m ? 0.0f : w;
    w1 = m ? w : 0.0f;
}

// Stage one 128x128B half-K tile pair into buf (8 global_load_lds / wave).
// PROVEN geometry: LDS slot lane-contiguous, global chunk cl = cp ^ swz(r).
__device__ inline void stage_tile(const unsigned char* __restrict__ pA,
                                  const unsigned char* __restrict__ pB,
                                  int k0, unsigned char* lA, unsigned char* lB,
                                  int tid)
{
    #pragma unroll
    for (int rnd = 0; rnd < 4; ++rnd) {
        const int slot = rnd * 4096 + tid * 16;
        const int r    = slot >> 7;
        const int cp   = (slot >> 4) & 7;
        const int cl   = cp ^ swz(r);
        load_lds16(pA + (size_t)r * DBYTES + k0 + cl * 16, lA + slot);
    }
    #pragma unroll
    for (int rnd = 0; rnd < 4; ++rnd) {
        const int slot = rnd * 4096 + tid * 16;
        const int r    = slot >> 7;
        const int cp   = (slot >> 4) & 7;
        const int cl   = cp ^ swz(r);
        load_lds16(pB + (size_t)r * DBYTES + k0 + cl * 16, lB + slot);
    }
}

// Persistent: 512 blocks x 256 thr (4 waves), 2 blocks/CU (64KB LDS).
// Per wave 64x64 output (2x2 of 32x32x64 fp4 MFMA). Unit = (job, kstage),
// kstage in {0,1} (k0 = 0/128B). Rolling double-buffer over units.
__global__ __launch_bounds__(256, 2) void gram_kernel(
    const unsigned char* __restrict__ A0,   // fp4 img [8192][256B]
    const unsigned char* __restrict__ A1,   // fp4 txt
    float* __restrict__ S)                  // [64] spread accumulators
{
    const int tid  = threadIdx.x;
    const int lane = tid & 63;
    const int wave = tid >> 6;
    const int wm = wave & 1, wn = wave >> 1;
    const int lr = lane & 31;                  // row-in-subtile
    const int h  = lane >> 5;                  // K-half select
    const int b  = blockIdx.x;

    __shared__ __align__(16) unsigned char ldsA[2][128 * 128];   // 32 KB
    __shared__ __align__(16) unsigned char ldsB[2][128 * 128];   // 32 KB
    __shared__ float ps[4][2];

    const int J = (NJOBS - 1 - b) / GRAMBLK + 1;   // 8 or 9 jobs
    const int U = 2 * J;

    float16v acc[2][2];
    #pragma unroll
    for (int a = 0; a < 2; ++a)
        #pragma unroll
        for (int c = 0; c < 2; ++c)
            #pragma unroll
            for (int r = 0; r < 16; ++r) acc[a][c][r] = 0.0f;
    float s0 = 0.0f, s1 = 0.0f;

    // prologue: decode job 0, stage its kstage-0 into buf 0
    const unsigned char *nA, *nB;
    float nw0, nw1;
    decode_job(b, A0, A1, nA, nB, nw0, nw1);
    float cw0 = nw0, cw1 = nw1;
    stage_tile(nA, nB, 0, ldsA[0], ldsB[0], tid);

    for (int u = 0; u < U; ++u) {
        const int buf = u & 1;
        if (u + 1 < U) {
            const int v = u + 1;
            if ((v & 1) == 0)   // next unit starts a new job
                decode_job(b + GRAMBLK * (v >> 1), A0, A1, nA, nB, nw0, nw1);
            stage_tile(nA, nB, (v & 1) * 128, ldsA[v & 1], ldsB[v & 1], tid);
            // unit u's 8 loads land; unit u+1's 8 stay in flight
            asm volatile("s_waitcnt vmcnt(8)" ::: "memory");
        } else {
            asm volatile("s_waitcnt vmcnt(0)" ::: "memory");
        }
        __builtin_amdgcn_sched_barrier(0);
        __builtin_amdgcn_s_barrier();          // B1: buf[u] complete for all
        __builtin_amdgcn_sched_barrier(0);

        const unsigned char* lA = ldsA[buf];
        const unsigned char* lB = ldsB[buf];
        #pragma unroll
        for (int kk = 0; kk < 4; ++kk) {       // four K=64 steps per unit
            const int c0 = kk * 2 + h;         // one 16B chunk per lane
            int8v av[2], bv[2];
            #pragma unroll
            for (int mt = 0; mt < 2; ++mt) {
                const int r = wm * 64 + mt * 32 + lr;
                *((int4v*)&av[mt]) =
                    *(const int4v*)&lA[r * 128 + (c0 ^ swz(r)) * 16];
                *((int4v*)&av[mt] + 1) = (int4v){0, 0, 0, 0};
            }
            #pragma unroll
            for (int nt = 0; nt < 2; ++nt) {
                const int r = wn * 64 + nt * 32 + lr;
                *((int4v*)&bv[nt]) =
                    *(const int4v*)&lB[r * 128 + (c0 ^ swz(r)) * 16];
                *((int4v*)&bv[nt] + 1) = (int4v){0, 0, 0, 0};
            }
            #pragma unroll
            for (int mt = 0; mt < 2; ++mt)
                #pragma unroll
                for (int nt = 0; nt < 2; ++nt)
                    acc[mt][nt] = __builtin_amdgcn_mfma_scale_f32_32x32x64_f8f6f4(
                        av[mt], bv[nt], acc[mt][nt],
                        4, 4,                   // cbsz=blgp=4: fp4 e2m1
                        0, SCALE4,              // opsel_a, scale_a (2^-4)
                        0, SCALE4);             // opsel_b, scale_b (2^-4)
        }

        if (u & 1) {   // job finished: fold into running sums, reset acc
            float f = 0.0f;
            #pragma unroll
            for (int mt = 0; mt < 2; ++mt)
                #pragma unroll
                for (int nt = 0; nt < 2; ++nt)
                    #pragma unroll
                    for (int r2 = 0; r2 < 16; ++r2) {
                        const float g = acc[mt][nt][r2];
                        f += __expf(4.0f * fminf(g, 1.0f) - 4.0f);
                        acc[mt][nt][r2] = 0.0f;
                    }
            s0 += cw0 * f;
            s1 += cw1 * f;
            cw0 = nw0;  cw1 = nw1;
        }

        __builtin_amdgcn_sched_barrier(0);
        __builtin_amdgcn_s_barrier();          // B2: all done reading buf[u]
    }

    // block reduce + one atomic per matrix per block
    #pragma unroll
    for (int off = 32; off; off >>= 1) {
        s0 += __shfl_down(s0, off);
        s1 += __shfl_down(s1, off);
    }
    if (lane == 0) { ps[wave][0] = s0; ps[wave][1] = s1; }
    __syncthreads();
    if (tid == 0) {
        atomicAdd(&S[b & 31],        ps[0][0] + ps[1][0] + ps[2][0] + ps[3][0]);
        atomicAdd(&S[32 + (b & 31)], ps[0][1] + ps[1][1] + ps[2][1] + ps[3][1]);
    }
}

// ---------------------------------------------------------------- finalize
__global__ __launch_bounds__(256) void finalize_kernel(
    const float* __restrict__ S,       // [64]
    const float* __restrict__ alignp,  // [2048]
    float* __restrict__ out)
{
    const int tid = threadIdx.x;
    float a = 0.0f;
    #pragma unroll
    for (int k = 0; k < 8; ++k) a += alignp[tid + 256 * k];
    #pragma unroll
    for (int off = 32; off; off >>= 1) a += __shfl_down(a, off);
    __shared__ float r4[4];
    if ((tid & 63) == 0) r4[tid >> 6] = a;
    __syncthreads();
    if (tid == 0) {
        const double A = (double)r4[0] + r4[1] + r4[2] + r4[3];
        double si = 0.0, st = 0.0;
        for (int k = 0; k < 32; ++k) { si += S[k]; st += S[32 + k]; }
        const double align = 2.0 - 2.0 * A / (double)NROWS;
        const double n2 = (double)NROWS * (double)NROWS;
        const double unif = 0.5 * (log(si / n2) + log(st / n2));
        out[0] = (float)(3.0 * align + unif);
    }
}

// ---------------------------------------------------------------- launch
extern "C" void kernel_launch(void* const* d_in, const int* in_sizes, int n_in,
                              void* d_out, int out_size, void* d_ws, size_t ws_size,
                              hipStream_t stream) {
    const float* img = (const float*)d_in[0];
    const float* txt = (const float*)d_in[1];
    char* ws = (char*)d_ws;
    int* nimg = (int*)ws;                                        // 2 MB fp4
    int* ntxt = (int*)(ws + (size_t)NROWS * DBYTES);             // 2 MB fp4
    float* S      = (float*)(ws + 2 * (size_t)NROWS * DBYTES);   // [64]
    float* alignp = S + 64;                                      // [2048]

    normalize_kernel<<<NROWS / 4, 256, 0, stream>>>(img, txt, nimg, ntxt, alignp, S);
    gram_kernel<<<GRAMBLK, 256, 0, stream>>>((const unsigned char*)nimg,
                                             (const unsigned char*)ntxt, S);
    finalize_kernel<<<1, 256, 0, stream>>>(S, alignp, (float*)d_out);
}